// Round 11
// baseline (189.727 us; speedup 1.0000x reference)
//
#include <hip/hip_runtime.h>
#include <math.h>

// VP-SDE Euler-Maruyama forward diffusion (fp32).
// out[0] = x; out[t+1] = a_t * out[t] + b_t * noise[t],  t = 0..99
//
// Ladder: R4/R9 178 (nt/nt reg ping-pong, f4/f2) | cached-ld variants 190-200
// (L2 thrash) | cached-st 183-185 | LDS-DMA 192.
// Facts: (1) nt path pinned at 4.5 TB/s across TLP/ILP; (2) R6 measured
// FETCH=202MB with cached loads -- noise stays L3-resident across replays
// (writes don't allocate in the memory-side cache), a ~200MB HBM subsidy.
// R11: producer/consumer wave split. Producers (2 waves) global_load_lds
// with CACHED reads (harvest L3 subsidy, absorb L2 latency); consumers
// (2 waves) ds_read+fma+nt-store with a store-only vmem queue that is never
// waited on (raw s_barrier, manual per-role waitcnt). 1 barrier/window.

#define S_STEPS 100
#define U 4                     // planes per window
#define NWIN (S_STEPS / U)      // 25 windows

typedef float f32x4 __attribute__((ext_vector_type(4)));

__device__ __forceinline__ void gl_lds16(const float* g, float* l) {
    // 16B/lane: LDS dest = wave-uniform base + lane*16; global src per-lane.
    // aux=0: CACHED read (L2/L3 allocate) -- deliberate, for the L3 subsidy.
    __builtin_amdgcn_global_load_lds(
        (const __attribute__((address_space(1))) unsigned int*)g,
        (__attribute__((address_space(3))) unsigned int*)l,
        16, 0, 0);
}

__global__ __launch_bounds__(256) void vpsde_fwd_kernel(
    const float* __restrict__ x,
    const float* __restrict__ noise,
    float* __restrict__ out,
    int ne)  // floats per timestep plane (1,048,576)
{
    // [buf][plane][512 floats]: 2KB tile per plane, double-buffered. 16 KB.
    __shared__ __align__(16) float s_noise[2][U][512];
    __shared__ float2 s_ab[S_STEPS];

    const int tid  = threadIdx.x;
    const int wid  = tid >> 6;      // 0,1 producers; 2,3 consumers
    const int lane = tid & 63;

    if (tid < S_STEPS) {
        const float dt = 0.01f;
        float nt_  = (float)tid * dt;            // (t-1)/S for t=1..S
        float beta = 0.1f + nt_ * 19.9f;
        s_ab[tid] = make_float2(1.0f - 0.5f * beta * dt,  // a_t
                                sqrtf(beta) * 0.1f);      // b_t
    }
    __syncthreads();   // barrier #0: s_ab visible

    const size_t plane = (size_t)ne;   // floats per plane
    const int    ne4   = ne >> 2;      // float4 per plane

    if (wid < 2) {
        // ---------- PRODUCER: vmem queue contains ONLY loads ----------
        // Covers 1KB of the block's 2KB/plane tile per wave.
        const float* gsrc = noise + (size_t)blockIdx.x * 512 + wid * 256
                          + lane * 4;

        // Prologue: window 0 -> buf 0, drain, then enter phase loop.
        #pragma unroll
        for (int k = 0; k < U; ++k)
            gl_lds16(gsrc + (size_t)k * plane, &s_noise[0][k][wid * 256]);
        gsrc += (size_t)U * plane;
        asm volatile("s_waitcnt vmcnt(0)" ::: "memory");

        for (int w = 0; w < NWIN; ++w) {
            __builtin_amdgcn_s_barrier();   // publish W_w; buf[(w+1)&1] free
            if (w + 1 < NWIN) {
                #pragma unroll
                for (int k = 0; k < U; ++k)
                    gl_lds16(gsrc + (size_t)k * plane,
                             &s_noise[(w + 1) & 1][k][wid * 256]);
                gsrc += (size_t)U * plane;
            }
            // Drain own (load-only) queue before next publish barrier.
            asm volatile("s_waitcnt vmcnt(0)" ::: "memory");
        }
    } else {
        // ---------- CONSUMER: vmem queue contains ONLY nt stores ----------
        const int    c  = (wid - 2) * 64 + lane;          // 0..127 float4
        const size_t g4 = (size_t)blockIdx.x * 128 + c;   // global float4 idx
        const f32x4* x4   = (const f32x4*)x;
        f32x4*       out4 = (f32x4*)out;

        f32x4 xv = x4[g4];
        __builtin_nontemporal_store(xv, out4 + g4);       // out[0] = x

        f32x4* dst = out4 + (size_t)ne4 + g4;             // out[t+1]
        int t = 0;
        for (int w = 0; w < NWIN; ++w) {
            __builtin_amdgcn_s_barrier();   // W_w ready in buf[w&1]
            f32x4 nv[U];
            #pragma unroll
            for (int k = 0; k < U; ++k)     // batch ds_reads for MLP
                nv[k] = *(const f32x4*)&s_noise[w & 1][k][c * 4];
            #pragma unroll
            for (int k = 0; k < U; ++k) {
                float2 ab = s_ab[t + k];
                xv = ab.x * xv + ab.y * nv[k];
                __builtin_nontemporal_store(xv, dst);     // never waited on
                dst += ne4;
            }
            t += U;
            // ds_reads fully consumed; make it explicit before the barrier
            // so producer may overwrite buf[w&1] next phase.
            asm volatile("s_waitcnt lgkmcnt(0)" ::: "memory");
        }
    }
}

extern "C" void kernel_launch(void* const* d_in, const int* in_sizes, int n_in,
                              void* d_out, int out_size, void* d_ws, size_t ws_size,
                              hipStream_t stream) {
    const float* x     = (const float*)d_in[0];   // (64,256,64)
    const float* noise = (const float*)d_in[1];   // (100,64,256,64)
    float* out         = (float*)d_out;           // (101,64,256,64)

    const int ne  = in_sizes[0];       // 1,048,576 floats per plane
    const int ne4 = ne / 4;            // 262,144 float4
    const int block = 256;             // 2 producer + 2 consumer waves
    const int grid  = ne4 / 128;       // 2048 blocks (tile = 128 float4)

    vpsde_fwd_kernel<<<grid, block, 0, stream>>>(x, noise, out, ne);
}

// Round 12
// 164.225 us; speedup vs baseline: 1.1553x; 1.1553x over previous
//
#include <hip/hip_runtime.h>
#include <math.h>

// VP-SDE Euler-Maruyama forward diffusion (fp32).
// out[0] = x; out[t+1] = a_t * out[t] + b_t * noise[t],  t = 0..99
//
// Ladder: R4 178.5 (f4 2-buf nt/nt) | R9 177.8 (f2, 32 w/CU) | all cached /
// LDS / producer-consumer / deep-ILP variants 183-192.
// Theory that fits ALL data: DRAM row thrash. Every wave hops 4MB between
// consecutive accesses; 8192 waves x thin 2KB slices -> thousands of active
// DRAM regions, oversubscribing open rows. (Also explains R8: 4 plane-hopping
// buffers = 20 active planes/wave = worst locality -> 192us.)
// R12: chunk-major layout. Each thread owns 2 float4; each WAVE covers 2KB
// CONTIGUOUS per plane (block: 8KB); 512 blocks -> 4x fewer, 4x fatter
// active regions. Depth-4 plane pipeline keeps 8 loads (8KB) in flight/wave.

#define S_STEPS 100
#define DEPTH 4                 // pipeline depth in planes

typedef float f32x4 __attribute__((ext_vector_type(4)));

__global__ __launch_bounds__(256) void vpsde_fwd_kernel(
    const f32x4* __restrict__ x,
    const f32x4* __restrict__ noise,
    f32x4* __restrict__ out,
    int ne4)  // float4 per plane (262,144)
{
    __shared__ float s_a[S_STEPS];
    __shared__ float s_b[S_STEPS];

    const int tid = threadIdx.x;
    if (tid < S_STEPS) {
        const float dt = 0.01f;
        float nt_ = (float)tid * dt;           // (t-1)/S for t=1..S
        float beta = 0.1f + nt_ * 19.9f;
        s_a[tid] = 1.0f - 0.5f * beta * dt;
        s_b[tid] = sqrtf(beta) * 0.1f;         // sqrt(beta)*sqrt(dt)
    }
    __syncthreads();

    const int wid  = tid >> 6;
    const int lane = tid & 63;

    // Chunk-major: wave covers 128 consecutive float4 (2KB) per plane.
    // lane's two chunks: base, base+64.
    const size_t base = (size_t)blockIdx.x * 512 + (size_t)wid * 128 + lane;

    const f32x4* gl = noise + base;        // running load ptr (plane t)
    f32x4*       st = out + base + ne4;    // running store ptr (plane t+1)

    f32x4 xv0 = x[base];
    f32x4 xv1 = x[base + 64];
    __builtin_nontemporal_store(xv0, out + base);        // out[0] = x
    __builtin_nontemporal_store(xv1, out + base + 64);

    int t = 0;                              // current plane index

    f32x4 A[2], B[2], C[2], Dq[2];

    auto loadp = [&](f32x4* buf) {          // one plane: 2 contiguous loads
        buf[0] = __builtin_nontemporal_load(gl);
        buf[1] = __builtin_nontemporal_load(gl + 64);
        gl += ne4;
    };
    auto consume = [&](const f32x4* buf) {  // fma + 2 contiguous stores
        const float a = s_a[t];
        const float b = s_b[t];
        xv0 = a * xv0 + b * buf[0];
        xv1 = a * xv1 + b * buf[1];
        __builtin_nontemporal_store(xv0, st);
        __builtin_nontemporal_store(xv1, st + 64);
        st += ne4;
        ++t;
    };

    // Prologue: 4 planes in flight (8 loads, 8KB/wave).
    loadp(A); loadp(B); loadp(C); loadp(Dq);

    // 24 cycles x 4 planes = 96 consumed; planes 4..99 loaded on the fly.
    #pragma unroll 1
    for (int cyc = 0; cyc < (S_STEPS / DEPTH) - 1; ++cyc) {
        consume(A);  loadp(A);
        consume(B);  loadp(B);
        consume(C);  loadp(C);
        consume(Dq); loadp(Dq);
    }
    // Epilogue: planes 96..99.
    consume(A); consume(B); consume(C); consume(Dq);
}

extern "C" void kernel_launch(void* const* d_in, const int* in_sizes, int n_in,
                              void* d_out, int out_size, void* d_ws, size_t ws_size,
                              hipStream_t stream) {
    const float* x     = (const float*)d_in[0];   // (64,256,64)
    const float* noise = (const float*)d_in[1];   // (100,64,256,64)
    float* out         = (float*)d_out;           // (101,64,256,64)

    const int ne  = in_sizes[0];       // 1,048,576 floats per plane
    const int ne4 = ne / 4;            // 262,144 float4 per plane

    const int block = 256;
    const int grid  = ne4 / 512;       // 512 blocks (block tile = 8KB/plane)

    vpsde_fwd_kernel<<<grid, block, 0, stream>>>(
        (const f32x4*)x, (const f32x4*)noise, (f32x4*)out, ne4);
}